// Round 4
// baseline (138.280 us; speedup 1.0000x reference)
//
#include <hip/hip_runtime.h>

// topk_mean pooling (k=2). patch_ids SORTED along seq -> each patch is a
// contiguous token run. Kernels identical to R3 (passing, absmax 0).
// DIAGNOSTIC ROUND: topk_mean_pool is launched 3x (idempotent, writes the
// same values each time) to measure its true per-dispatch cost:
//   T_main = (dur_R4 - dur_R3) / 2
// since the rocprof top-5 is saturated by ~42us harness poison fills and we
// cannot otherwise see our kernel's duration.

#define NEG_INF (-1.0e9f)

__global__ __launch_bounds__(256) void seg_bounds(
    const int* __restrict__ pid,
    const int* __restrict__ d_P,
    int*       __restrict__ bnd,   // [pairs] lower_bound_b(p)
    int bs_seq, int pairs)
{
    const int P   = *d_P;
    const int bs  = pairs / P;
    const int seq = bs_seq / bs;

    const int pair = blockIdx.x * blockDim.x + threadIdx.x;
    if (pair >= pairs) return;
    const int b = pair / P;
    const int p = pair - b * P;
    const int* row = pid + (size_t)b * seq;
    int lo = 0, hi = seq;
    while (lo < hi) {
        const int mid = (lo + hi) >> 1;
        if (row[mid] < p) lo = mid + 1; else hi = mid;
    }
    bnd[pair] = lo;
}

__global__ __launch_bounds__(128) void topk_mean_pool(
    const float* __restrict__ h,
    const int*   __restrict__ bnd,
    const int*   __restrict__ d_P,
    const int*   __restrict__ d_k,
    float*       __restrict__ out,
    int bs_seq, int pairs, int E)
{
    const int P   = *d_P;
    const int bs  = pairs / P;
    const int seq = bs_seq / bs;
    const int kk  = *d_k;

    const int pair = blockIdx.x;     // pair = b*P + p
    const int b    = pair / P;
    const int p    = pair - b * P;

    const int start = bnd[pair];
    const int end   = (p == P - 1) ? seq : bnd[pair + 1];
    const int n     = end - start;

    const int Ed4 = E >> 2;          // 128 for E=512
    const float4* hb   = (const float4*)h + (size_t)b * seq * Ed4;
    float4*       out4 = (float4*)out + (size_t)pair * Ed4;

    for (int c = threadIdx.x; c < Ed4; c += blockDim.x) {
        float4 r;
        if (n == 0) {
            r = make_float4(0.f, 0.f, 0.f, 0.f);
        } else {
            float4 m1 = make_float4(-INFINITY, -INFINITY, -INFINITY, -INFINITY);
            float4 m2 = m1;
            float4 v = hb[(size_t)start * Ed4 + c];
            for (int t = start; t < end; ++t) {
                float4 vn = v;
                const int tn = t + 1;
                if (tn < end) vn = hb[(size_t)tn * Ed4 + c];
                if (v.x > m1.x) { m2.x = m1.x; m1.x = v.x; }
                else if (v.x < m1.x && v.x > m2.x) { m2.x = v.x; }
                if (v.y > m1.y) { m2.y = m1.y; m1.y = v.y; }
                else if (v.y < m1.y && v.y > m2.y) { m2.y = v.y; }
                if (v.z > m1.z) { m2.z = m1.z; m1.z = v.z; }
                else if (v.z < m1.z && v.z > m2.z) { m2.z = v.z; }
                if (v.w > m1.w) { m2.w = m1.w; m1.w = v.w; }
                else if (v.w < m1.w && v.w > m2.w) { m2.w = v.w; }
                v = vn;
            }
            if (n == 1 || kk == 1) {
                r = m1;
            } else {
                r.x = 0.5f * (m1.x + fmaxf(m2.x, NEG_INF));
                r.y = 0.5f * (m1.y + fmaxf(m2.y, NEG_INF));
                r.z = 0.5f * (m1.z + fmaxf(m2.z, NEG_INF));
                r.w = 0.5f * (m1.w + fmaxf(m2.w, NEG_INF));
            }
        }
        out4[c] = r;
    }
}

extern "C" void kernel_launch(void* const* d_in, const int* in_sizes, int n_in,
                              void* d_out, int out_size, void* d_ws, size_t ws_size,
                              hipStream_t stream) {
    const float* h   = (const float*)d_in[0];
    const int*   pid = (const int*)d_in[1];
    const int*   d_P = (const int*)d_in[2];
    const int*   d_k = (const int*)d_in[3];
    float*       out = (float*)d_out;
    int*         bnd = (int*)d_ws;

    const int h_elems = in_sizes[0];       // bs*seq*E
    const int bs_seq  = in_sizes[1];       // bs*seq
    const int E       = h_elems / bs_seq;  // 512
    const int pairs   = out_size / E;      // bs*P

    {
        dim3 grid((pairs + 255) / 256), block(256);
        seg_bounds<<<grid, block, 0, stream>>>(pid, d_P, bnd, bs_seq, pairs);
    }
    // 3x identical launches (idempotent) — timing diagnostic, see header.
    for (int rep = 0; rep < 3; ++rep) {
        dim3 grid(pairs), block(128);
        topk_mean_pool<<<grid, block, 0, stream>>>(h, bnd, d_P, d_k, out,
                                                   bs_seq, pairs, E);
    }
}

// Round 5
// 110.313 us; speedup vs baseline: 1.2535x; 1.2535x over previous
//
#include <hip/hip_runtime.h>

// topk_mean pooling (k=2). patch_ids are SORTED along seq, so each patch is a
// contiguous token run. Two kernels:
//   A) seg_bounds: one thread per (b,p) does lower_bound(p) on the sorted row,
//      writes to d_ws (L2-hot, latency overlapped across waves).
//   B) topk_mean_pool: one block (128 thr) per (b,p); boundaries come from two
//      uniform scalar loads; token loop software-pipelined 2-deep.
// Measured (R4 diagnostic, 3x-launch delta): topk_mean_pool ~= 14.3 us/dispatch
// vs 12.7 us traffic floor (64 MB read + 16 MB write @ 6.3 TB/s) -> ~89% of
// achievable BW. Reported dur_us (~110) is dominated by fixed harness
// restore/poison traffic (268 MB ws fill = 42 us etc.), not this kernel.
// Semantics (faithful to reference): m1 = max over run; m2 = max over values
// STRICTLY below m1 (reference masks ALL copies of the max with -1e9);
//   n==0 -> 0 ; n==1 or k==1 -> m1 ; n>=2 -> 0.5*(m1 + max(m2, -1e9)).

#define NEG_INF (-1.0e9f)

__global__ __launch_bounds__(256) void seg_bounds(
    const int* __restrict__ pid,
    const int* __restrict__ d_P,
    int*       __restrict__ bnd,   // [pairs] lower_bound_b(p)
    int bs_seq, int pairs)
{
    const int P   = *d_P;
    const int bs  = pairs / P;
    const int seq = bs_seq / bs;

    const int pair = blockIdx.x * blockDim.x + threadIdx.x;
    if (pair >= pairs) return;
    const int b = pair / P;
    const int p = pair - b * P;
    const int* row = pid + (size_t)b * seq;
    int lo = 0, hi = seq;
    while (lo < hi) {
        const int mid = (lo + hi) >> 1;
        if (row[mid] < p) lo = mid + 1; else hi = mid;
    }
    bnd[pair] = lo;
}

__global__ __launch_bounds__(128) void topk_mean_pool(
    const float* __restrict__ h,
    const int*   __restrict__ bnd,
    const int*   __restrict__ d_P,
    const int*   __restrict__ d_k,
    float*       __restrict__ out,
    int bs_seq, int pairs, int E)
{
    const int P   = *d_P;
    const int bs  = pairs / P;
    const int seq = bs_seq / bs;
    const int kk  = *d_k;

    const int pair = blockIdx.x;     // pair = b*P + p
    const int b    = pair / P;
    const int p    = pair - b * P;

    // Uniform (blockIdx-only) -> scalar loads.
    const int start = bnd[pair];
    const int end   = (p == P - 1) ? seq : bnd[pair + 1];
    const int n     = end - start;

    const int Ed4 = E >> 2;          // 128 for E=512
    const float4* hb   = (const float4*)h + (size_t)b * seq * Ed4;
    float4*       out4 = (float4*)out + (size_t)pair * Ed4;

    for (int c = threadIdx.x; c < Ed4; c += blockDim.x) {
        float4 r;
        if (n == 0) {
            r = make_float4(0.f, 0.f, 0.f, 0.f);
        } else {
            float4 m1 = make_float4(-INFINITY, -INFINITY, -INFINITY, -INFINITY);
            float4 m2 = m1;
            // 2-deep software pipeline: next row load in flight while the
            // current one is consumed.
            float4 v = hb[(size_t)start * Ed4 + c];
            for (int t = start; t < end; ++t) {
                float4 vn = v;
                const int tn = t + 1;
                if (tn < end) vn = hb[(size_t)tn * Ed4 + c];
                if (v.x > m1.x) { m2.x = m1.x; m1.x = v.x; }
                else if (v.x < m1.x && v.x > m2.x) { m2.x = v.x; }
                if (v.y > m1.y) { m2.y = m1.y; m1.y = v.y; }
                else if (v.y < m1.y && v.y > m2.y) { m2.y = v.y; }
                if (v.z > m1.z) { m2.z = m1.z; m1.z = v.z; }
                else if (v.z < m1.z && v.z > m2.z) { m2.z = v.z; }
                if (v.w > m1.w) { m2.w = m1.w; m1.w = v.w; }
                else if (v.w < m1.w && v.w > m2.w) { m2.w = v.w; }
                v = vn;
            }
            if (n == 1 || kk == 1) {
                r = m1;
            } else {
                r.x = 0.5f * (m1.x + fmaxf(m2.x, NEG_INF));
                r.y = 0.5f * (m1.y + fmaxf(m2.y, NEG_INF));
                r.z = 0.5f * (m1.z + fmaxf(m2.z, NEG_INF));
                r.w = 0.5f * (m1.w + fmaxf(m2.w, NEG_INF));
            }
        }
        out4[c] = r;
    }
}

extern "C" void kernel_launch(void* const* d_in, const int* in_sizes, int n_in,
                              void* d_out, int out_size, void* d_ws, size_t ws_size,
                              hipStream_t stream) {
    const float* h   = (const float*)d_in[0];
    const int*   pid = (const int*)d_in[1];
    const int*   d_P = (const int*)d_in[2];
    const int*   d_k = (const int*)d_in[3];
    float*       out = (float*)d_out;
    int*         bnd = (int*)d_ws;

    const int h_elems = in_sizes[0];       // bs*seq*E
    const int bs_seq  = in_sizes[1];       // bs*seq
    const int E       = h_elems / bs_seq;  // 512
    const int pairs   = out_size / E;      // bs*P

    {
        dim3 grid((pairs + 255) / 256), block(256);
        seg_bounds<<<grid, block, 0, stream>>>(pid, d_P, bnd, bs_seq, pairs);
    }
    {
        dim3 grid(pairs), block(128);
        topk_mean_pool<<<grid, block, 0, stream>>>(h, bnd, d_P, d_k, out,
                                                   bs_seq, pairs, E);
    }
}